// Round 11
// baseline (429.543 us; speedup 1.0000x reference)
//
#include <hip/hip_runtime.h>

#define DEVI __device__ __forceinline__

typedef unsigned short u16;
typedef unsigned int   u32;
typedef __attribute__((ext_vector_type(8))) short short8;
typedef __attribute__((ext_vector_type(4))) short short4b;
typedef __attribute__((ext_vector_type(4))) float f32x4;

// ---------- bf16 helpers (bit ops, RNE) ----------
DEVI float bf2f(u16 u) {
    union { u32 i; float f; } x; x.i = ((u32)u) << 16; return x.f;
}
DEVI u16 f2bf(float f) {
    u32 u = __float_as_uint(f);
    u32 r = (u + 0x7FFFu + ((u >> 16) & 1u)) >> 16;
    return (u16)r;
}

DEVI void gload_lds16(const void* g, void* l) {
    __builtin_amdgcn_global_load_lds((const __attribute__((address_space(1))) void*)g,
                                     (__attribute__((address_space(3))) void*)l, 16, 0, 0);
}

// =====================================================================
// Weight transpose jobs: dst(bf16, N x K row-major) = src(f32, K x N)^T
// =====================================================================
struct PJob { u32 dst, soff, tbase, ld, Kd, src; };
__device__ const PJob g_jobs[19] = {
    {0,        0,      0,    128, 64,  4},
    {8192,     0,      8,    512, 256, 0},
    {139264,   131072, 136,  512, 256, 0},
    {270336,   262144, 264,  512, 128, 0},
    {335872,   0,      328,  256, 512, 1},
    {466944,   0,      456,  512, 512, 2},
    {729088,   0,      712,  256, 512, 3},
    {860160,   327680, 840,  512, 256, 0},
    {991232,   458752, 968,  512, 256, 0},
    {1122304,  589824, 1096, 512, 128, 0},
    {1187840,  131072, 1160, 256, 512, 1},
    {1318912,  262144, 1288, 512, 512, 2},
    {1581056,  131072, 1544, 256, 512, 3},
    {1712128,  655360, 1672, 512, 256, 0},
    {1843200,  786432, 1800, 512, 256, 0},
    {1974272,  917504, 1928, 512, 128, 0},
    {2039808,  262144, 1992, 256, 512, 1},
    {2170880,  524288, 2120, 512, 512, 2},
    {2433024,  262144, 2376, 256, 512, 3},
};

// =====================================================================
// SETUP mega-kernel (all 256-thread jobs, disjoint outputs):
//   blocks [0,2504)      : prep_weights (transpose+bf16 of all GEMM weights)
//   blocks [2504,10696)  : transpose_in  x(B,C,N) f32 -> feats(B,N,C) bf16
//   blocks [10696,10824) : edge_h        (edge-vec MLP layer 1)
//   blocks [10824,11208) : conv_w2       (mW2 f32 -> bf16, fused path only)
// =====================================================================
__global__ __launch_bounds__(256) void setup_kernel(
    const float* __restrict__ x, u16* __restrict__ feats,
    const float* __restrict__ points, const int* __restrict__ nb,
    const float* __restrict__ eW1, const float* __restrict__ eb1,
    u16* __restrict__ hEdge,
    const float* __restrict__ mW1, const float* __restrict__ mW2,
    const float* __restrict__ uW1, const float* __restrict__ uW2,
    const float* __restrict__ eW2,
    u16* __restrict__ wreg, u16* __restrict__ mW2bf)
{
    __shared__ float tile[32][33];
    int bid = blockIdx.x;
    int t = threadIdx.x;
    int tx = t & 31, ty = t >> 5;

    if (bid < 2504) {
        // ---- prep_weights ----
        int ji = 0;
        #pragma unroll
        for (int i = 1; i < 19; ++i) if (bid >= (int)g_jobs[i].tbase) ji = i;
        PJob jb = g_jobs[ji];
        const float* src = (jb.src == 0) ? mW1 : (jb.src == 1) ? mW2 : (jb.src == 2) ? uW1
                         : (jb.src == 3) ? uW2 : eW2;
        src += jb.soff;
        int tt = bid - (int)jb.tbase;
        int nk = (int)jb.Kd >> 5;
        int tk = tt % nk, tj = tt / nk;
        int k0 = tk * 32, j0 = tj * 32;
        #pragma unroll
        for (int yy = 0; yy < 4; ++yy) {
            int k = k0 + ty + yy * 8;
            tile[ty + yy * 8][tx] = src[(size_t)k * jb.ld + j0 + tx];
        }
        __syncthreads();
        u16* dst = wreg + jb.dst;
        #pragma unroll
        for (int yy = 0; yy < 4; ++yy) {
            int j = j0 + ty + yy * 8;
            dst[(size_t)j * jb.Kd + k0 + tx] = f2bf(tile[tx][ty + yy * 8]);
        }
    } else if (bid < 10696) {
        // ---- transpose_in ----
        int bb = bid - 2504;
        int n0 = (bb & 255) * 32, c0 = ((bb >> 8) & 7) * 32, b = bb >> 11;
        #pragma unroll
        for (int yy = 0; yy < 4; ++yy) {
            int c = c0 + ty + yy * 8;
            tile[ty + yy * 8][tx] = x[((size_t)b * 256 + c) * 8192 + n0 + tx];
        }
        __syncthreads();
        #pragma unroll
        for (int yy = 0; yy < 4; ++yy) {
            int n = n0 + ty + yy * 8;
            feats[((size_t)b * 8192 + n) * 256 + c0 + tx] = f2bf(tile[tx][ty + yy * 8]);
        }
    } else if (bid < 10824) {
        // ---- edge_h ----
        int e = (bid - 10696) * 256 + t;     // 32768 edges
        int n = e >> 2;
        int j2 = nb[e];
        float p0x = points[n * 3], p0y = points[n * 3 + 1], p0z = points[n * 3 + 2];
        float v0 = points[j2 * 3]     - p0x;
        float v1 = points[j2 * 3 + 1] - p0y;
        float v2 = points[j2 * 3 + 2] - p0z;
        #pragma unroll
        for (int jb2 = 0; jb2 < 8; ++jb2) {
            short8 o;
            #pragma unroll
            for (int jj = 0; jj < 8; ++jj) {
                int j = jb2 * 8 + jj;
                float hv = v0 * eW1[j] + v1 * eW1[64 + j] + v2 * eW1[128 + j] + eb1[j];
                o[jj] = (short)f2bf(fmaxf(hv, 0.0f));
            }
            *(short8*)&hEdge[(size_t)e * 64 + jb2 * 8] = o;
        }
    } else {
        // ---- conv_w2 ----
        int i = (bid - 10824) * 256 + t;     // 98304 threads
        float4 v = *(const float4*)&mW2[(size_t)i * 4];
        short4b o;
        o[0] = (short)f2bf(v.x); o[1] = (short)f2bf(v.y);
        o[2] = (short)f2bf(v.z); o[3] = (short)f2bf(v.w);
        *(short4b*)&mW2bf[(size_t)i * 4] = o;
    }
}

// ub1c[l*512+n] = ub1[l*512+n] + sum_j mb2[l*256+j] * U1T_l[n][256+j]
__global__ __launch_bounds__(256) void biasfix(const u16* __restrict__ wreg,
    const float* __restrict__ mb2, const float* __restrict__ ub1,
    float* __restrict__ ub1c)
{
    int idx = blockIdx.x * 256 + threadIdx.x;   // 0..1535
    int l = idx >> 9, n = idx & 511;
    const u16* U1T = wreg + 8192 + l * 851968 + 458752;
    const float* b2 = mb2 + l * 256;
    float s = ub1[l * 512 + n];
    for (int j0 = 0; j0 < 256; j0 += 8) {
        short8 wv = *(const short8*)&U1T[(size_t)n * 512 + 256 + j0];
        #pragma unroll
        for (int jj = 0; jj < 8; ++jj) s += bf2f((u16)wv[jj]) * b2[j0 + jj];
    }
    ub1c[idx] = s;
}

// =====================================================================
// bf16 MFMA GEMM, two-job merged dispatch.
// 512 threads / 8 waves on a 256x128 tile: wave grid 4M x 2N, each wave a
// 64x64 sub-tile (4x4 frags of 16x16x32) -> 8 ds_read_b128 : 16 MFMA per
// wave K-step (0.5 reads/MFMA, m97 golden ratio) and 128 MFMA per
// barrier-pair. BK=32, LDS 48KB (2 bufs x [A 16KB | B 8KB]),
// depth-2 counted-vmcnt pipeline (steady wait vmcnt(3), never 0 until last),
// raw s_barrier x2 per K-step, XOR chunk swizzle (pre-swizzled global src,
// linear LDS, swizzled ds_read), setprio around MFMA cluster.
// Epilogue repacks through LDS in two 128-row halves.
// C = [A1|A2] @ [B1|B2]^T (+bias, relu). K1,Ktot multiples of 32.
// Blocks [0,nbx0) run job g0, the rest job g1 (per-job XCD swizzle).
// Per-job flattened batching: bpb>0 -> by = bxl/bpb, strides sA/sB/sC.
// permrows=1: output row m stored at row (m&8191)*4 + (m>>13).
// transout=1: C is f32 (B,C,N); tile stored transposed (fused transpose_out).
// =====================================================================
struct GArgs {
    const u16* A1; const u16* A2; const u16* B1; const u16* B2;
    const float* bias; u16* C;
    long sA, sB, sC;
    int lda1, K1, lda2, ldb1, ldb2, ldc, nbn, Ktot, relu, permrows, transout, bpb;
};

__global__ __launch_bounds__(512, 4) void gemm_bt(GArgs g0, GArgs g1, int nbx0)
{
    __shared__ u16 lds[24576];         // 49152 B: buf d at d*12288 u16 = [A 16KB | B 8KB]
    int bx0 = (int)blockIdx.x;
    bool j0 = bx0 < nbx0;
    GArgs g = j0 ? g0 : g1;
    int nwgj = j0 ? nbx0 : ((int)gridDim.x - nbx0);
    int bxl  = j0 ? bx0 : bx0 - nbx0;

    const u16* A1 = g.A1; const u16* A2 = g.A2;
    const u16* B1 = g.B1; const u16* B2 = g.B2;
    u16* Cp = g.C;
    if (g.bpb > 0) {                               // flattened batching
        int by = bxl / g.bpb;
        bxl -= by * g.bpb;
        nwgj = g.bpb;
        A1 += (long)by * g.sA; A2 += (long)by * g.sA;
        B1 += (long)by * g.sB; B2 += (long)by * g.sB;
        Cp += (long)by * g.sC;
    }
    int bx = (bxl & 7) * (nwgj >> 3) + (bxl >> 3); // bijective XCD swizzle (nwgj%8==0)
    int tn = bx % g.nbn, tm = bx / g.nbn;
    int t = threadIdx.x;
    int l = t & 63, w = t >> 6;                     // 8 waves: 4M x 2N, each 64x64
    int wrow = (w >> 1) * 64, wcol = (w & 1) * 64;
    int lm = l & 15, lk = l >> 4;
    int sOff = ((lk ^ ((lm >> 1) & 3)) << 3);       // swizzled read slot (u16 units)
    int rowA = tm * 256;
    int rowB = tn * 128;

    f32x4 acc[4][4];
    #pragma unroll
    for (int mi = 0; mi < 4; ++mi)
        #pragma unroll
        for (int ni = 0; ni < 4; ++ni)
            acc[mi][ni] = (f32x4){0.f, 0.f, 0.f, 0.f};

    int nks  = g.Ktot >> 5;
    int nksw = (g.K1 < g.Ktot) ? (g.K1 >> 5) : 0x7fffffff;  // region-switch tile

    // strength-reduced staging pointers (advance +32 per staged K-tile)
    // A: 1024 chunks (256 rows x 4 slots) = 2 loads/thread; B: 512 = 1/thread
    int rS = t >> 2;                                // row 0..127
    int cS = (t & 3) ^ ((rS >> 1) & 3);             // pre-swizzled global chunk
    const u16* pA  = A1 + (size_t)(rowA + rS) * g.lda1 + cS * 8;
    const u16* pA2 = A1 + (size_t)(rowA + 128 + rS) * g.lda1 + cS * 8;
    const u16* pB  = B1 + (size_t)(rowB + rS) * g.ldb1 + cS * 8;
    int st = 0;                                     // next K-tile index to stage
    auto STAGE = [&]() {
        if (st == nksw) {                           // enter A2/B2 region (kg resets to 0)
            pA  = A2 + (size_t)(rowA + rS) * g.lda2 + cS * 8;
            pA2 = A2 + (size_t)(rowA + 128 + rS) * g.lda2 + cS * 8;
            pB  = B2 + (size_t)(rowB + rS) * g.ldb2 + cS * 8;
        }
        u16* At = lds + (st & 1) * 12288;
        u16* Bt = At + 8192;
        gload_lds16(pA,  &At[t * 8]);          pA  += 32;
        gload_lds16(pA2, &At[(512 + t) * 8]);  pA2 += 32;
        gload_lds16(pB,  &Bt[t * 8]);          pB  += 32;
        ++st;
    };

    STAGE();
    if (nks > 1) STAGE();
    int cur = 0;
    for (int ks = 0; ks < nks; ++ks) {
        // barrier 1: K-tile ks's 3 loads/thread landed; ks+1's stay in flight
        if (ks + 1 < nks) asm volatile("s_waitcnt vmcnt(3)\n\ts_barrier" ::: "memory");
        else              asm volatile("s_waitcnt vmcnt(0)\n\ts_barrier" ::: "memory");
        const u16* At = lds + cur * 12288;
        const u16* Bt = At + 8192;
        __builtin_amdgcn_s_setprio(1);
        {
            short8 af[4], bv[4];
            #pragma unroll
            for (int mi = 0; mi < 4; ++mi)
                af[mi] = *(const short8*)&At[(wrow + mi * 16 + lm) * 32 + sOff];
            #pragma unroll
            for (int ni = 0; ni < 4; ++ni)
                bv[ni] = *(const short8*)&Bt[(wcol + ni * 16 + lm) * 32 + sOff];
            #pragma unroll
            for (int mi = 0; mi < 4; ++mi)
                #pragma unroll
                for (int ni = 0; ni < 4; ++ni)
                    acc[mi][ni] = __builtin_amdgcn_mfma_f32_16x16x32_bf16(af[mi], bv[ni], acc[mi][ni], 0, 0, 0);
        }
        __builtin_amdgcn_s_setprio(0);
        // barrier 2: all waves' ds_reads of buf cur complete (lgkmcnt before MFMAs)
        asm volatile("s_barrier" ::: "memory");
        if (st < nks) STAGE();                      // overwrite just-consumed buffer
        cur ^= 1;
    }

    // ---- epilogue: two 128-row halves through LDS (34.8KB <= 48KB staging)
    // stride 136 (normal) / 134 (transout: 67 odd -> column reads conflict-free)
    int str = g.transout ? 134 : 136;
    #pragma unroll
    for (int h = 0; h < 2; ++h) {
        if ((wrow >> 7) == h) {                    // waves owning rows [h*128, h*128+128)
            int wr = wrow & 127;
            #pragma unroll
            for (int ni = 0; ni < 4; ++ni) {
                int col = wcol + ni * 16 + lm;
                float bvl = g.bias ? g.bias[tn * 128 + col] : 0.0f;
                #pragma unroll
                for (int mi = 0; mi < 4; ++mi) {
                    int row0 = wr + mi * 16 + lk * 4;
                    f32x4 v = acc[mi][ni];
                    #pragma unroll
                    for (int r = 0; r < 4; ++r) {
                        float f = v[r] + bvl;
                        if (g.relu) f = fmaxf(f, 0.0f);
                        lds[(row0 + r) * str + col] = f2bf(f);
                    }
                }
            }
        }
        __syncthreads();
        if (g.transout) {
            // tile rows m = tm*256 + h*128 + row; b = tm>>5, n0 = (tm&31)*256 + h*128
            // out f32 (B,C,N): wave lanes -> consecutive n (256B contiguous stores)
            // 128 rows x 128 cols = 16384 f32 = 512 threads x 32
            float* Co = (float*)Cp;
            int b  = tm >> 5;
            int n0 = (tm & 31) * 256 + h * 128;
            int c0 = tn * 128;
            #pragma unroll
            for (int p = 0; p < 32; ++p) {
                int row = (t & 63) + ((p & 1) << 6);
                int col = (t >> 6) + ((p >> 1) << 3);
                float f = bf2f(lds[row * 134 + col]);
                Co[((size_t)b * 256 + c0 + col) * 8192 + n0 + row] = f;
            }
        } else {
            #pragma unroll
            for (int p = 0; p < 4; ++p) {
                int chunk = p * 512 + t;          // 0..2047 = 128 rows x 16 slots
                int row = chunk >> 4, sl = chunk & 15;
                short8 v = *(const short8*)&lds[row * 136 + sl * 8];
                int m = tm * 256 + h * 128 + row;
                int orow = g.permrows ? (((m & 8191) << 2) | (m >> 13)) : m;
                *(short8*)&Cp[(size_t)orow * g.ldc + tn * 128 + sl * 8] = v;
            }
        }
        __syncthreads();
    }
}

// =====================================================================
// hbar[b,n,:] = 0.25 * sum_k relu(P[b,nb[n,k],:] + R[b,n,:] + E[n,k,:] + b1)
// PR rows permuted (n*4+b). ALL 16 random P loads + 4 R loads issued before
// any consumption (latency-bound fix); E streamed per node (L2-friendly).
// =====================================================================
__global__ __launch_bounds__(256, 3) void gather_relu_mean(
    const u16* __restrict__ PR, const u16* __restrict__ E,
    const int* __restrict__ nb, const float* __restrict__ b1,
    u16* __restrict__ hbar)
{
    int b = threadIdx.x >> 6, l = threadIdx.x & 63;
    int c0 = l * 8;
    int n0 = blockIdx.x * 4;

    int nbarr[4][4];
    #pragma unroll
    for (int ii = 0; ii < 4; ++ii) {
        int4 v = *(const int4*)&nb[(n0 + ii) * 4];
        nbarr[ii][0] = v.x; nbarr[ii][1] = v.y; nbarr[ii][2] = v.z; nbarr[ii][3] = v.w;
    }

    // issue all 16 gathered P loads + 4 R loads up front
    short8 pv[4][4];
    #pragma unroll
    for (int ii = 0; ii < 4; ++ii)
        #pragma unroll
        for (int k = 0; k < 4; ++k)
            pv[ii][k] = *(const short8*)&PR[(size_t)(nbarr[ii][k] * 4 + b) * 1024 + c0];
    short8 rv[4];
    #pragma unroll
    for (int ii = 0; ii < 4; ++ii)
        rv[ii] = *(const short8*)&PR[(size_t)((n0 + ii) * 4 + b) * 1024 + 512 + c0];

    float4 b1a = *(const float4*)&b1[c0];
    float4 b1b = *(const float4*)&b1[c0 + 4];
    float bb[8] = {b1a.x, b1a.y, b1a.z, b1a.w, b1b.x, b1b.y, b1b.z, b1b.w};

    #pragma unroll
    for (int ii = 0; ii < 4; ++ii) {
        int n = n0 + ii;
        short8 ev[4];
        #pragma unroll
        for (int k = 0; k < 4; ++k)
            ev[k] = *(const short8*)&E[(size_t)(n * 4 + k) * 512 + c0];

        float base[8], acc[8];
        #pragma unroll
        for (int j = 0; j < 8; ++j) { base[j] = bf2f((u16)rv[ii][j]) + bb[j]; acc[j] = 0.0f; }
        #pragma unroll
        for (int k = 0; k < 4; ++k) {
            #pragma unroll
            for (int j = 0; j < 8; ++j) {
                float v = bf2f((u16)pv[ii][k][j]) + bf2f((u16)ev[k][j]) + base[j];
                acc[j] += fmaxf(v, 0.0f);
            }
        }
        short8 o;
        #pragma unroll
        for (int j = 0; j < 8; ++j) o[j] = (short)f2bf(acc[j] * 0.25f);
        *(short8*)&hbar[((size_t)(b << 13) + n) * 512 + c0] = o;
    }
}

// =====================================================================
static inline GArgs mkargs(const u16* A1, int lda1, int K1, const u16* A2, int lda2,
                           const u16* B1, int ldb1, const u16* B2, int ldb2,
                           const float* bias, u16* C, int ldc,
                           int nbn, int Ktot, int relu, int permrows,
                           int transout = 0, int bpb = 0,
                           long sA = 0, long sB = 0, long sC = 0)
{
    GArgs g;
    g.A1 = A1; g.A2 = A2; g.B1 = B1; g.B2 = B2; g.bias = bias; g.C = C;
    g.sA = sA; g.sB = sB; g.sC = sC;
    g.lda1 = lda1; g.K1 = K1; g.lda2 = lda2; g.ldb1 = ldb1; g.ldb2 = ldb2;
    g.ldc = ldc; g.nbn = nbn; g.Ktot = Ktot; g.relu = relu; g.permrows = permrows;
    g.transout = transout; g.bpb = bpb;
    return g;
}

extern "C" void kernel_launch(void* const* d_in, const int* in_sizes, int n_in,
                              void* d_out, int out_size, void* d_ws, size_t ws_size,
                              hipStream_t stream)
{
    const float* x      = (const float*)d_in[0];
    const float* points = (const float*)d_in[1];
    const int*   nb     = (const int*)d_in[2];
    const float* eW1    = (const float*)d_in[3];
    const float* eb1    = (const float*)d_in[4];
    const float* eW2    = (const float*)d_in[5];
    const float* eb2    = (const float*)d_in[6];
    const float* mW1    = (const float*)d_in[7];
    const float* mb1    = (const float*)d_in[8];
    const float* mW2    = (const float*)d_in[9];
    const float* mb2    = (const float*)d_in[10];
    const float* uW1    = (const float*)d_in[11];
    const float* ub1    = (const float*)d_in[12];
    const float* uW2    = (const float*)d_in[13];
    const float* ub2    = (const float*)d_in[14];
    float* out = (float*)d_out;

    char* ws = (char*)d_ws;
    // workspace layout (bytes)
    u16* featsA = (u16*)(ws);                          // 16,777,216
    u16* featsB = (u16*)(ws + 16777216);               // 16,777,216
    u16* ef     = (u16*)(ws + 33554432);               //  8,388,608
    u16* PR     = (u16*)(ws + 41943040);               // 67,108,864
    u16* E      = (u16*)(ws + 109051904);              // 33,554,432
    u16* hbar   = (u16*)(ws + 142606336);              // 33,554,432
    u16* wreg   = (u16*)(ws + 176160768);              //  5,128,192  (ends 181,288,960)
    // fused-path extras (+2,365,440 bytes -> 183,654,400 total)
    u16*   mW2bf = (u16*)(ws + 181288960);             //    786,432
    u16*   WcT   = (u16*)(ws + 182075392);             //  1,572,864
    float* ub1c  = (float*)(ws + 183648256);           //      6,144
    u16* hEdge  = PR;     // alias: dead before layer-0 GEMM1
    u16* H2     = PR;     // alias: PR dead after gather
    u16* agg    = E;      // alias (non-fused path): E dead after gather

    const bool fused = (ws_size >= 183654400ull);

    // setup: prep_weights + transpose_in + edge_h (+ conv_w2 when fused)
    setup_kernel<<<fused ? 11208 : 10824, 256, 0, stream>>>(
        x, featsA, points, nb, eW1, eb1, hEdge,
        mW1, mW2, uW1, uW2, eW2, wreg, mW2bf);

    if (fused) {
        biasfix<<<6, 256, 0, stream>>>(wreg, mb2, ub1, ub1c);
        // merged: job0 = ef GEMM (128 blocks), job1 = WcT batched x3 (24 blocks)
        // ef  = h @ eW2 + eb2 : M=32768, N=128, K=64
        // WcT_l(512x512) = U1bT_l(512x256) @ mW2bf_l(512x256)^T'  (bpb=8)
        const u16* U1T0 = wreg + 8192 + 458752;
        GArgs gef = mkargs(hEdge, 64, 64, hEdge, 64, wreg, 64, wreg, 64,
                           eb2, ef, 128, 1, 64, 0, 0);
        GArgs gwc = mkargs(U1T0 + 256, 512, 256, U1T0, 512, mW2bf, 256, mW2bf, 256,
                           nullptr, WcT, 512, 4, 256, 0, 0, 0, 8,
                           851968, 131072, 262144);
        gemm_bt<<<152, 512, 0, stream>>>(gef, gwc, 128);
    } else {
        GArgs gef = mkargs(hEdge, 64, 64, hEdge, 64, wreg, 64, wreg, 64,
                           eb2, ef, 128, 1, 64, 0, 0);
        gemm_bt<<<128, 512, 0, stream>>>(gef, gef, 128);
    }

    const u16* fin = featsA; u16* fout = featsB;
    for (int lyr = 0; lyr < 3; ++lyr) {
        u16* W1abT = wreg + 8192 + lyr * 851968;
        u16* W1cT  = W1abT + 262144;
        u16* W2T   = W1abT + 327680;
        u16* U1T   = W1abT + 458752;
        u16* U2T   = W1abT + 720896;
        const float* b1  = mb1 + lyr * 512;
        const float* b2  = mb2 + lyr * 256;
        const float* u1b = ub1 + lyr * 512;
        const float* u2b = ub2 + lyr * 256;
        const bool last = (lyr == 2);

        // merged dispatch: job0 = PR GEMM (1024 blocks), job1 = E GEMM (512 blocks)
        // PR = feats @ [W1a|W1b]  (M=32768, N=1024, K=256), rows stored (n*4+b)
        // E  = ef @ W1c           (M=32768, N=512,  K=128)
        {
            GArgs gPR = mkargs((const u16*)fin, 256, 256, (const u16*)fin, 256,
                               W1abT, 256, W1abT, 256, nullptr, PR, 1024, 8, 256, 0, 1);
            GArgs gE  = mkargs(ef, 128, 128, ef, 128, W1cT, 128, W1cT, 128,
                               nullptr, E, 512, 4, 128, 0, 0);
            gemm_bt<<<1536, 512, 0, stream>>>(gPR, gE, 1024);
        }
        // hbar = mean_k relu(P_gather + R + E + b1)
        gather_relu_mean<<<2048, 256, 0, stream>>>(PR, E, nb, b1, hbar);

        if (fused) {
            // H2 = relu(feats@U1a + hbar@Wc + ub1c)  (M=32768, N=512, K=256+512)
            GArgs g = mkargs((const u16*)fin, 256, 256, hbar, 512,
                             U1T, 512, WcT + lyr * 262144, 512,
                             ub1c + lyr * 512, H2, 512, 4, 768, 1, 0);
            gemm_bt<<<512, 512, 0, stream>>>(g, g, 512);
        } else {
            // agg = hbar @ W2 + b2  (M=32768, N=256, K=512)
            GArgs ga = mkargs(hbar, 512, 512, hbar, 512, W2T, 512, W2T, 512,
                              b2, agg, 256, 2, 512, 0, 0);
            gemm_bt<<<256, 512, 0, stream>>>(ga, ga, 256);
            // H2 = relu([feats|agg] @ U1 + ub1)  (M=32768, N=512, K=256+256)
            GArgs gh = mkargs((const u16*)fin, 256, 256, agg, 256,
                              U1T, 512, U1T + 256, 512,
                              u1b, H2, 512, 4, 512, 1, 0);
            gemm_bt<<<512, 512, 0, stream>>>(gh, gh, 512);
        }
        // feats' = H2 @ U2 + ub2  (M=32768, N=256, K=512)
        // last layer: store f32 transposed directly to out (fused transpose_out)
        {
            GArgs g = mkargs(H2, 512, 512, H2, 512, U2T, 512, U2T, 512,
                             u2b, last ? (u16*)out : fout, 256, 2, 512, 0, 0,
                             last ? 1 : 0);
            gemm_bt<<<256, 512, 0, stream>>>(g, g, 256);
        }

        const u16* tmp = fin; fin = fout; fout = (u16*)tmp;
    }
}

// Round 12
// 393.602 us; speedup vs baseline: 1.0913x; 1.0913x over previous
//
#include <hip/hip_runtime.h>

#define DEVI __device__ __forceinline__

typedef unsigned short u16;
typedef unsigned int   u32;
typedef __attribute__((ext_vector_type(8))) short short8;
typedef __attribute__((ext_vector_type(4))) short short4b;
typedef __attribute__((ext_vector_type(4))) float f32x4;

// ---------- bf16 helpers (bit ops, RNE) ----------
DEVI float bf2f(u16 u) {
    union { u32 i; float f; } x; x.i = ((u32)u) << 16; return x.f;
}
DEVI u16 f2bf(float f) {
    u32 u = __float_as_uint(f);
    u32 r = (u + 0x7FFFu + ((u >> 16) & 1u)) >> 16;
    return (u16)r;
}

DEVI void gload_lds16(const void* g, void* l) {
    __builtin_amdgcn_global_load_lds((const __attribute__((address_space(1))) void*)g,
                                     (__attribute__((address_space(3))) void*)l, 16, 0, 0);
}

// =====================================================================
// Weight transpose jobs: dst(bf16, N x K row-major) = src(f32, K x N)^T
// =====================================================================
struct PJob { u32 dst, soff, tbase, ld, Kd, src; };
__device__ const PJob g_jobs[19] = {
    {0,        0,      0,    128, 64,  4},
    {8192,     0,      8,    512, 256, 0},
    {139264,   131072, 136,  512, 256, 0},
    {270336,   262144, 264,  512, 128, 0},
    {335872,   0,      328,  256, 512, 1},
    {466944,   0,      456,  512, 512, 2},
    {729088,   0,      712,  256, 512, 3},
    {860160,   327680, 840,  512, 256, 0},
    {991232,   458752, 968,  512, 256, 0},
    {1122304,  589824, 1096, 512, 128, 0},
    {1187840,  131072, 1160, 256, 512, 1},
    {1318912,  262144, 1288, 512, 512, 2},
    {1581056,  131072, 1544, 256, 512, 3},
    {1712128,  655360, 1672, 512, 256, 0},
    {1843200,  786432, 1800, 512, 256, 0},
    {1974272,  917504, 1928, 512, 128, 0},
    {2039808,  262144, 1992, 256, 512, 1},
    {2170880,  524288, 2120, 512, 512, 2},
    {2433024,  262144, 2376, 256, 512, 3},
};

// =====================================================================
// SETUP mega-kernel (all 256-thread jobs, disjoint outputs):
//   blocks [0,2504)      : prep_weights (transpose+bf16 of all GEMM weights)
//   blocks [2504,10696)  : transpose_in  x(B,C,N) f32 -> feats(B,N,C) bf16
//   blocks [10696,10824) : edge_h        (edge-vec MLP layer 1)
//   blocks [10824,11208) : conv_w2       (mW2 f32 -> bf16, fused path only)
// =====================================================================
__global__ __launch_bounds__(256) void setup_kernel(
    const float* __restrict__ x, u16* __restrict__ feats,
    const float* __restrict__ points, const int* __restrict__ nb,
    const float* __restrict__ eW1, const float* __restrict__ eb1,
    u16* __restrict__ hEdge,
    const float* __restrict__ mW1, const float* __restrict__ mW2,
    const float* __restrict__ uW1, const float* __restrict__ uW2,
    const float* __restrict__ eW2,
    u16* __restrict__ wreg, u16* __restrict__ mW2bf)
{
    __shared__ float tile[32][33];
    int bid = blockIdx.x;
    int t = threadIdx.x;
    int tx = t & 31, ty = t >> 5;

    if (bid < 2504) {
        // ---- prep_weights ----
        int ji = 0;
        #pragma unroll
        for (int i = 1; i < 19; ++i) if (bid >= (int)g_jobs[i].tbase) ji = i;
        PJob jb = g_jobs[ji];
        const float* src = (jb.src == 0) ? mW1 : (jb.src == 1) ? mW2 : (jb.src == 2) ? uW1
                         : (jb.src == 3) ? uW2 : eW2;
        src += jb.soff;
        int tt = bid - (int)jb.tbase;
        int nk = (int)jb.Kd >> 5;
        int tk = tt % nk, tj = tt / nk;
        int k0 = tk * 32, j0 = tj * 32;
        #pragma unroll
        for (int yy = 0; yy < 4; ++yy) {
            int k = k0 + ty + yy * 8;
            tile[ty + yy * 8][tx] = src[(size_t)k * jb.ld + j0 + tx];
        }
        __syncthreads();
        u16* dst = wreg + jb.dst;
        #pragma unroll
        for (int yy = 0; yy < 4; ++yy) {
            int j = j0 + ty + yy * 8;
            dst[(size_t)j * jb.Kd + k0 + tx] = f2bf(tile[tx][ty + yy * 8]);
        }
    } else if (bid < 10696) {
        // ---- transpose_in ----
        int bb = bid - 2504;
        int n0 = (bb & 255) * 32, c0 = ((bb >> 8) & 7) * 32, b = bb >> 11;
        #pragma unroll
        for (int yy = 0; yy < 4; ++yy) {
            int c = c0 + ty + yy * 8;
            tile[ty + yy * 8][tx] = x[((size_t)b * 256 + c) * 8192 + n0 + tx];
        }
        __syncthreads();
        #pragma unroll
        for (int yy = 0; yy < 4; ++yy) {
            int n = n0 + ty + yy * 8;
            feats[((size_t)b * 8192 + n) * 256 + c0 + tx] = f2bf(tile[tx][ty + yy * 8]);
        }
    } else if (bid < 10824) {
        // ---- edge_h ----
        int e = (bid - 10696) * 256 + t;     // 32768 edges
        int n = e >> 2;
        int j2 = nb[e];
        float p0x = points[n * 3], p0y = points[n * 3 + 1], p0z = points[n * 3 + 2];
        float v0 = points[j2 * 3]     - p0x;
        float v1 = points[j2 * 3 + 1] - p0y;
        float v2 = points[j2 * 3 + 2] - p0z;
        #pragma unroll
        for (int jb2 = 0; jb2 < 8; ++jb2) {
            short8 o;
            #pragma unroll
            for (int jj = 0; jj < 8; ++jj) {
                int j = jb2 * 8 + jj;
                float hv = v0 * eW1[j] + v1 * eW1[64 + j] + v2 * eW1[128 + j] + eb1[j];
                o[jj] = (short)f2bf(fmaxf(hv, 0.0f));
            }
            *(short8*)&hEdge[(size_t)e * 64 + jb2 * 8] = o;
        }
    } else {
        // ---- conv_w2 ----
        int i = (bid - 10824) * 256 + t;     // 98304 threads
        float4 v = *(const float4*)&mW2[(size_t)i * 4];
        short4b o;
        o[0] = (short)f2bf(v.x); o[1] = (short)f2bf(v.y);
        o[2] = (short)f2bf(v.z); o[3] = (short)f2bf(v.w);
        *(short4b*)&mW2bf[(size_t)i * 4] = o;
    }
}

// ub1c[l*512+n] = ub1[l*512+n] + sum_j mb2[l*256+j] * U1T_l[n][256+j]
__global__ __launch_bounds__(256) void biasfix(const u16* __restrict__ wreg,
    const float* __restrict__ mb2, const float* __restrict__ ub1,
    float* __restrict__ ub1c)
{
    int idx = blockIdx.x * 256 + threadIdx.x;   // 0..1535
    int l = idx >> 9, n = idx & 511;
    const u16* U1T = wreg + 8192 + l * 851968 + 458752;
    const float* b2 = mb2 + l * 256;
    float s = ub1[l * 512 + n];
    for (int j0 = 0; j0 < 256; j0 += 8) {
        short8 wv = *(const short8*)&U1T[(size_t)n * 512 + 256 + j0];
        #pragma unroll
        for (int jj = 0; jj < 8; ++jj) s += bf2f((u16)wv[jj]) * b2[j0 + jj];
    }
    ub1c[idx] = s;
}

// =====================================================================
// bf16 MFMA GEMM, two-job merged dispatch, templated on BK.
// 512 threads / 8 waves on a 128x128 tile (wave = 64x32 out).
// BK=32: LDS 34.8KB -> 4 blocks/CU (TLP regime; best for short-K, measured
//        r9: PR+E 38.8us @59% occ). vmcnt(2) steady.
// BK=64: LDS 64KB -> 2 blocks/CU, half the barrier pairs (best for long-K,
//        measured r8: H2/U2). vmcnt(4) steady.
// Depth-2 counted-vmcnt pipeline (never drain to 0 until last), raw
// s_barrier x2 per K-step, XOR chunk swizzle (pre-swizzled global src,
// linear LDS, swizzled ds_read), setprio around MFMA cluster.
// C = [A1|A2] @ [B1|B2]^T (+bias, relu). K1,Ktot multiples of BK.
// Blocks [0,nbx0) run job g0, the rest job g1 (per-job XCD swizzle).
// Per-job flattened batching: bpb>0 -> by = bxl/bpb, strides sA/sB/sC.
// permrows=1: output row m stored at row (m&8191)*4 + (m>>13).
// transout=1: C is f32 (B,C,N); tile stored transposed (fused transpose_out).
// Identical MFMA K-order for both BK -> bitwise-identical outputs.
// =====================================================================
struct GArgs {
    const u16* A1; const u16* A2; const u16* B1; const u16* B2;
    const float* bias; u16* C;
    long sA, sB, sC;
    int lda1, K1, lda2, ldb1, ldb2, ldc, nbn, Ktot, relu, permrows, transout, bpb;
};

template<int BK>
__global__ __launch_bounds__(512, BK == 32 ? 8 : 4) void gemm_bt(GArgs g0, GArgs g1, int nbx0)
{
    constexpr int SLOTS = BK / 8;               // 16B chunks per row
    constexpr int LPT   = BK / 32;              // loads/thread per array per tile
    constexpr int BUFU  = 256 * BK;             // u16 per dbuf entry [A|B]
    __shared__ u16 lds[BK == 32 ? 17408 : 32768];
    int bx0 = (int)blockIdx.x;
    bool j0 = bx0 < nbx0;
    GArgs g = j0 ? g0 : g1;
    int nwgj = j0 ? nbx0 : ((int)gridDim.x - nbx0);
    int bxl  = j0 ? bx0 : bx0 - nbx0;

    const u16* A1 = g.A1; const u16* A2 = g.A2;
    const u16* B1 = g.B1; const u16* B2 = g.B2;
    u16* Cp = g.C;
    if (g.bpb > 0) {                               // flattened batching
        int by = bxl / g.bpb;
        bxl -= by * g.bpb;
        nwgj = g.bpb;
        A1 += (long)by * g.sA; A2 += (long)by * g.sA;
        B1 += (long)by * g.sB; B2 += (long)by * g.sB;
        Cp += (long)by * g.sC;
    }
    int bx = (bxl & 7) * (nwgj >> 3) + (bxl >> 3); // bijective XCD swizzle (nwgj%8==0)
    int tn = bx % g.nbn, tm = bx / g.nbn;
    int t = threadIdx.x;
    int l = t & 63, w = t >> 6;                     // 8 waves: 2M x 4N, each 64x32
    int wrow = (w >> 2) * 64, wcol = (w & 3) * 32;
    int lm = l & 15, lk = l >> 4;
    int rowA = tm * 128;
    int rowB = tn * 128;

    f32x4 acc[4][2];
    #pragma unroll
    for (int mi = 0; mi < 4; ++mi)
        #pragma unroll
        for (int ni = 0; ni < 2; ++ni)
            acc[mi][ni] = (f32x4){0.f, 0.f, 0.f, 0.f};

    int nks  = g.Ktot / BK;
    int nksw = (g.K1 < g.Ktot) ? (g.K1 / BK) : 0x7fffffff;  // region-switch tile

    // strength-reduced staging pointers (advance +BK per staged K-tile)
    int rr[LPT], cc[LPT];
    const u16* pA[LPT]; const u16* pB[LPT];
    #pragma unroll
    for (int i = 0; i < LPT; ++i) {
        int chunk = i * 512 + t;                    // 128 rows x SLOTS
        int r, s;
        if constexpr (BK == 64) { r = chunk >> 3; s = chunk & 7; }
        else                    { r = chunk >> 2; s = chunk & 3; }
        int c = (BK == 64) ? (s ^ (r & 7)) : (s ^ ((r >> 1) & 3));  // pre-swizzle
        rr[i] = r; cc[i] = c;
        pA[i] = A1 + (size_t)(rowA + r) * g.lda1 + c * 8;
        pB[i] = B1 + (size_t)(rowB + r) * g.ldb1 + c * 8;
    }
    int st = 0;                                     // next K-tile index to stage
    auto STAGE = [&]() {
        if (st == nksw) {                           // enter A2/B2 region (kg resets to 0)
            #pragma unroll
            for (int i = 0; i < LPT; ++i) {
                pA[i] = A2 + (size_t)(rowA + rr[i]) * g.lda2 + cc[i] * 8;
                pB[i] = B2 + (size_t)(rowB + rr[i]) * g.ldb2 + cc[i] * 8;
            }
        }
        u16* At = lds + (st & 1) * BUFU;
        u16* Bt = At + 128 * BK;
        #pragma unroll
        for (int i = 0; i < LPT; ++i) {
            int chunk = i * 512 + t;
            gload_lds16(pA[i], &At[chunk * 8]); pA[i] += BK;
            gload_lds16(pB[i], &Bt[chunk * 8]); pB[i] += BK;
        }
        ++st;
    };

    STAGE();
    if (nks > 1) STAGE();
    int cur = 0;
    for (int ks = 0; ks < nks; ++ks) {
        // barrier 1: tile ks's 2*LPT loads/thread landed; ks+1's stay in flight
        if (ks + 1 < nks) {
            if constexpr (BK == 64) asm volatile("s_waitcnt vmcnt(4)\n\ts_barrier" ::: "memory");
            else                    asm volatile("s_waitcnt vmcnt(2)\n\ts_barrier" ::: "memory");
        } else {
            asm volatile("s_waitcnt vmcnt(0)\n\ts_barrier" ::: "memory");
        }
        const u16* At = lds + cur * BUFU;
        const u16* Bt = At + 128 * BK;
        __builtin_amdgcn_s_setprio(1);
        #pragma unroll
        for (int ksub = 0; ksub < BK / 32; ++ksub) {
            int sOff;
            if constexpr (BK == 64) sOff = (((ksub << 2) | lk) ^ (lm & 7)) << 3;
            else                    sOff = (lk ^ ((lm >> 1) & 3)) << 3;
            short8 af[4], bv[2];
            #pragma unroll
            for (int mi = 0; mi < 4; ++mi)
                af[mi] = *(const short8*)&At[(wrow + mi * 16 + lm) * BK + sOff];
            #pragma unroll
            for (int ni = 0; ni < 2; ++ni)
                bv[ni] = *(const short8*)&Bt[(wcol + ni * 16 + lm) * BK + sOff];
            #pragma unroll
            for (int mi = 0; mi < 4; ++mi)
                #pragma unroll
                for (int ni = 0; ni < 2; ++ni)
                    acc[mi][ni] = __builtin_amdgcn_mfma_f32_16x16x32_bf16(af[mi], bv[ni], acc[mi][ni], 0, 0, 0);
        }
        __builtin_amdgcn_s_setprio(0);
        // barrier 2: all waves' ds_reads of buf cur complete (lgkmcnt before MFMAs)
        asm volatile("s_barrier" ::: "memory");
        if (st < nks) STAGE();                      // overwrite just-consumed buffer
        cur ^= 1;
    }

    // ---- epilogue: bias+relu -> bf16 -> LDS -> coalesced stores
    // stride 136 (normal) / 134 (transout: 67 odd -> column reads conflict-free)
    int str = g.transout ? 134 : 136;
    #pragma unroll
    for (int ni = 0; ni < 2; ++ni) {
        int col = wcol + ni * 16 + lm;
        float bvl = g.bias ? g.bias[tn * 128 + col] : 0.0f;
        #pragma unroll
        for (int mi = 0; mi < 4; ++mi) {
            int row0 = wrow + mi * 16 + lk * 4;
            f32x4 v = acc[mi][ni];
            #pragma unroll
            for (int r = 0; r < 4; ++r) {
                float f = v[r] + bvl;
                if (g.relu) f = fmaxf(f, 0.0f);
                lds[(row0 + r) * str + col] = f2bf(f);
            }
        }
    }
    __syncthreads();
    if (g.transout) {
        // rows m = (b<<13)+n: b = tm>>6, n0 = (tm&63)*128; cols c0 = tn*128.
        // out f32 (B,C,N): wave lanes -> consecutive n (256B contiguous stores)
        float* Co = (float*)Cp;
        int b  = tm >> 6;
        int n0 = (tm & 63) * 128;
        int c0 = tn * 128;
        #pragma unroll
        for (int p = 0; p < 32; ++p) {
            int row = (t & 63) + ((p & 1) << 6);
            int col = (t >> 6) + ((p >> 1) << 3);
            float f = bf2f(lds[row * 134 + col]);
            Co[((size_t)b * 256 + c0 + col) * 8192 + n0 + row] = f;
        }
    } else {
        #pragma unroll
        for (int p = 0; p < 4; ++p) {
            int chunk = p * 512 + t;          // 0..2047
            int row = chunk >> 4, sl = chunk & 15;
            short8 v = *(const short8*)&lds[row * 136 + sl * 8];
            int m = tm * 128 + row;
            int orow = g.permrows ? (((m & 8191) << 2) | (m >> 13)) : m;
            *(short8*)&Cp[(size_t)orow * g.ldc + tn * 128 + sl * 8] = v;
        }
    }
}

// =====================================================================
// hbar[b,n,:] = 0.25 * sum_k relu(P[b,nb[n,k],:] + R[b,n,:] + E[n,k,:] + b1)
// PR rows permuted (n*4+b). ALL 16 random P loads + 4 R loads issued before
// any consumption (latency-bound fix); E streamed per node (L2-friendly).
// =====================================================================
__global__ __launch_bounds__(256, 3) void gather_relu_mean(
    const u16* __restrict__ PR, const u16* __restrict__ E,
    const int* __restrict__ nb, const float* __restrict__ b1,
    u16* __restrict__ hbar)
{
    int b = threadIdx.x >> 6, l = threadIdx.x & 63;
    int c0 = l * 8;
    int n0 = blockIdx.x * 4;

    int nbarr[4][4];
    #pragma unroll
    for (int ii = 0; ii < 4; ++ii) {
        int4 v = *(const int4*)&nb[(n0 + ii) * 4];
        nbarr[ii][0] = v.x; nbarr[ii][1] = v.y; nbarr[ii][2] = v.z; nbarr[ii][3] = v.w;
    }

    // issue all 16 gathered P loads + 4 R loads up front
    short8 pv[4][4];
    #pragma unroll
    for (int ii = 0; ii < 4; ++ii)
        #pragma unroll
        for (int k = 0; k < 4; ++k)
            pv[ii][k] = *(const short8*)&PR[(size_t)(nbarr[ii][k] * 4 + b) * 1024 + c0];
    short8 rv[4];
    #pragma unroll
    for (int ii = 0; ii < 4; ++ii)
        rv[ii] = *(const short8*)&PR[(size_t)((n0 + ii) * 4 + b) * 1024 + 512 + c0];

    float4 b1a = *(const float4*)&b1[c0];
    float4 b1b = *(const float4*)&b1[c0 + 4];
    float bb[8] = {b1a.x, b1a.y, b1a.z, b1a.w, b1b.x, b1b.y, b1b.z, b1b.w};

    #pragma unroll
    for (int ii = 0; ii < 4; ++ii) {
        int n = n0 + ii;
        short8 ev[4];
        #pragma unroll
        for (int k = 0; k < 4; ++k)
            ev[k] = *(const short8*)&E[(size_t)(n * 4 + k) * 512 + c0];

        float base[8], acc[8];
        #pragma unroll
        for (int j = 0; j < 8; ++j) { base[j] = bf2f((u16)rv[ii][j]) + bb[j]; acc[j] = 0.0f; }
        #pragma unroll
        for (int k = 0; k < 4; ++k) {
            #pragma unroll
            for (int j = 0; j < 8; ++j) {
                float v = bf2f((u16)pv[ii][k][j]) + bf2f((u16)ev[k][j]) + base[j];
                acc[j] += fmaxf(v, 0.0f);
            }
        }
        short8 o;
        #pragma unroll
        for (int j = 0; j < 8; ++j) o[j] = (short)f2bf(acc[j] * 0.25f);
        *(short8*)&hbar[((size_t)(b << 13) + n) * 512 + c0] = o;
    }
}

// =====================================================================
static inline GArgs mkargs(const u16* A1, int lda1, int K1, const u16* A2, int lda2,
                           const u16* B1, int ldb1, const u16* B2, int ldb2,
                           const float* bias, u16* C, int ldc,
                           int nbn, int Ktot, int relu, int permrows,
                           int transout = 0, int bpb = 0,
                           long sA = 0, long sB = 0, long sC = 0)
{
    GArgs g;
    g.A1 = A1; g.A2 = A2; g.B1 = B1; g.B2 = B2; g.bias = bias; g.C = C;
    g.sA = sA; g.sB = sB; g.sC = sC;
    g.lda1 = lda1; g.K1 = K1; g.lda2 = lda2; g.ldb1 = ldb1; g.ldb2 = ldb2;
    g.ldc = ldc; g.nbn = nbn; g.Ktot = Ktot; g.relu = relu; g.permrows = permrows;
    g.transout = transout; g.bpb = bpb;
    return g;
}

extern "C" void kernel_launch(void* const* d_in, const int* in_sizes, int n_in,
                              void* d_out, int out_size, void* d_ws, size_t ws_size,
                              hipStream_t stream)
{
    const float* x      = (const float*)d_in[0];
    const float* points = (const float*)d_in[1];
    const int*   nb     = (const int*)d_in[2];
    const float* eW1    = (const float*)d_in[3];
    const float* eb1    = (const float*)d_in[4];
    const float* eW2    = (const float*)d_in[5];
    const float* eb2    = (const float*)d_in[6];
    const float* mW1    = (const float*)d_in[7];
    const float* mb1    = (const float*)d_in[8];
    const float* mW2    = (const float*)d_in[9];
    const float* mb2    = (const float*)d_in[10];
    const float* uW1    = (const float*)d_in[11];
    const float* ub1    = (const float*)d_in[12];
    const float* uW2    = (const float*)d_in[13];
    const float* ub2    = (const float*)d_in[14];
    float* out = (float*)d_out;

    char* ws = (char*)d_ws;
    // workspace layout (bytes)
    u16* featsA = (u16*)(ws);                          // 16,777,216
    u16* featsB = (u16*)(ws + 16777216);               // 16,777,216
    u16* ef     = (u16*)(ws + 33554432);               //  8,388,608
    u16* PR     = (u16*)(ws + 41943040);               // 67,108,864
    u16* E      = (u16*)(ws + 109051904);              // 33,554,432
    u16* hbar   = (u16*)(ws + 142606336);              // 33,554,432
    u16* wreg   = (u16*)(ws + 176160768);              //  5,128,192  (ends 181,288,960)
    // fused-path extras (+2,365,440 bytes -> 183,654,400 total)
    u16*   mW2bf = (u16*)(ws + 181288960);             //    786,432
    u16*   WcT   = (u16*)(ws + 182075392);             //  1,572,864
    float* ub1c  = (float*)(ws + 183648256);           //      6,144
    u16* hEdge  = PR;     // alias: dead before layer-0 GEMM1
    u16* H2     = PR;     // alias: PR dead after gather
    u16* agg    = E;      // alias (non-fused path): E dead after gather

    const bool fused = (ws_size >= 183654400ull);

    // setup: prep_weights + transpose_in + edge_h (+ conv_w2 when fused)
    setup_kernel<<<fused ? 11208 : 10824, 256, 0, stream>>>(
        x, featsA, points, nb, eW1, eb1, hEdge,
        mW1, mW2, uW1, uW2, eW2, wreg, mW2bf);

    if (fused) {
        biasfix<<<6, 256, 0, stream>>>(wreg, mb2, ub1, ub1c);
        // merged: job0 = ef GEMM (256 blocks), job1 = WcT batched x3 (48 blocks)
        // ef  = h @ eW2 + eb2 : M=32768, N=128, K=64
        // WcT_l(512x512) = U1bT_l(512x256) @ mW2bf_l(512x256)^T'
        const u16* U1T0 = wreg + 8192 + 458752;
        GArgs gef = mkargs(hEdge, 64, 64, hEdge, 64, wreg, 64, wreg, 64,
                           eb2, ef, 128, 1, 64, 0, 0);
        GArgs gwc = mkargs(U1T0 + 256, 512, 256, U1T0, 512, mW2bf, 256, mW2bf, 256,
                           nullptr, WcT, 512, 4, 256, 0, 0, 0, 16,
                           851968, 131072, 262144);
        gemm_bt<64><<<304, 512, 0, stream>>>(gef, gwc, 256);
    } else {
        GArgs gef = mkargs(hEdge, 64, 64, hEdge, 64, wreg, 64, wreg, 64,
                           eb2, ef, 128, 1, 64, 0, 0);
        gemm_bt<64><<<256, 512, 0, stream>>>(gef, gef, 256);
    }

    const u16* fin = featsA; u16* fout = featsB;
    for (int lyr = 0; lyr < 3; ++lyr) {
        u16* W1abT = wreg + 8192 + lyr * 851968;
        u16* W1cT  = W1abT + 262144;
        u16* W2T   = W1abT + 327680;
        u16* U1T   = W1abT + 458752;
        u16* U2T   = W1abT + 720896;
        const float* b1  = mb1 + lyr * 512;
        const float* b2  = mb2 + lyr * 256;
        const float* u1b = ub1 + lyr * 512;
        const float* u2b = ub2 + lyr * 256;
        const bool last = (lyr == 2);

        // merged dispatch (BK=32, high-occupancy regime — r9 measured best):
        // job0 = PR GEMM (2048 blocks), job1 = E GEMM (1024 blocks)
        // PR = feats @ [W1a|W1b]  (M=32768, N=1024, K=256), rows stored (n*4+b)
        // E  = ef @ W1c           (M=32768, N=512,  K=128)
        {
            GArgs gPR = mkargs((const u16*)fin, 256, 256, (const u16*)fin, 256,
                               W1abT, 256, W1abT, 256, nullptr, PR, 1024, 8, 256, 0, 1);
            GArgs gE  = mkargs(ef, 128, 128, ef, 128, W1cT, 128, W1cT, 128,
                               nullptr, E, 512, 4, 128, 0, 0);
            gemm_bt<32><<<3072, 512, 0, stream>>>(gPR, gE, 2048);
        }
        // hbar = mean_k relu(P_gather + R + E + b1)
        gather_relu_mean<<<2048, 256, 0, stream>>>(PR, E, nb, b1, hbar);

        if (fused) {
            // H2 = relu(feats@U1a + hbar@Wc + ub1c)  (M=32768, N=512, K=256+512)
            GArgs g = mkargs((const u16*)fin, 256, 256, hbar, 512,
                             U1T, 512, WcT + lyr * 262144, 512,
                             ub1c + lyr * 512, H2, 512, 4, 768, 1, 0);
            gemm_bt<64><<<1024, 512, 0, stream>>>(g, g, 1024);
        } else {
            // agg = hbar @ W2 + b2  (M=32768, N=256, K=512)
            GArgs ga = mkargs(hbar, 512, 512, hbar, 512, W2T, 512, W2T, 512,
                              b2, agg, 256, 2, 512, 0, 0);
            gemm_bt<64><<<512, 512, 0, stream>>>(ga, ga, 512);
            // H2 = relu([feats|agg] @ U1 + ub1)  (M=32768, N=512, K=256+256)
            GArgs gh = mkargs((const u16*)fin, 256, 256, agg, 256,
                              U1T, 512, U1T + 256, 512,
                              u1b, H2, 512, 4, 512, 1, 0);
            gemm_bt<64><<<1024, 512, 0, stream>>>(gh, gh, 1024);
        }
        // feats' = H2 @ U2 + ub2  (M=32768, N=256, K=512)
        // last layer: store f32 transposed directly to out (fused transpose_out)
        {
            GArgs g = mkargs(H2, 512, 512, H2, 512, U2T, 512, U2T, 512,
                             u2b, last ? (u16*)out : fout, 256, 2, 512, 0, 0,
                             last ? 1 : 0);
            gemm_bt<64><<<512, 512, 0, stream>>>(g, g, 512);
        }

        const u16* tmp = fin; fin = fout; fout = (u16*)tmp;
    }
}